// Round 3
// baseline (527.732 us; speedup 1.0000x reference)
//
#include <hip/hip_runtime.h>
#include <stdint.h>

#define B_ 4
#define L_ 2048
#define H_ 8
#define E_ 64
#define S_ 2048

typedef __bf16 bf16x8 __attribute__((ext_vector_type(8)));
typedef _Float16 f16x8 __attribute__((ext_vector_type(8)));
typedef _Float16 f16x2 __attribute__((ext_vector_type(2)));
typedef float f32x4 __attribute__((ext_vector_type(4)));
typedef unsigned short u16;
typedef u16 u16x4 __attribute__((ext_vector_type(4)));
typedef uint32_t u32;

__device__ __forceinline__ u16 f32_to_bf16(float f) {
  union { float f; uint32_t u; } x;
  x.f = f;
  uint32_t u = x.u;
  return (u16)((u + 0x7FFFu + ((u >> 16) & 1u)) >> 16);
}

// q' = bf16(q * tau[b]/sqrt(E) * log2(e)), k' = bf16(k), delta' = delta/sqrt(E)*log2(e)
__global__ __launch_bounds__(256) void prep_qkd(
    const float* __restrict__ q, const float* __restrict__ k,
    const float* __restrict__ tau, const float* __restrict__ delta,
    u16* __restrict__ qb, u16* __restrict__ kb, float* __restrict__ dl) {
  int idx = blockIdx.x * 256 + threadIdx.x;  // 0 .. 1048575
  int i4 = idx * 4;
  int b = i4 >> 20;
  const float C = 0.125f * 1.44269504088896f;
  float ts = tau[b] * C;
  f32x4 qv = *(const f32x4*)(q + i4);
  f32x4 kv = *(const f32x4*)(k + i4);
  u16x4 qs, ks;
#pragma unroll
  for (int j = 0; j < 4; ++j) {
    qs[j] = f32_to_bf16(qv[j] * ts);
    ks[j] = f32_to_bf16(kv[j]);
  }
  *(u16x4*)(qb + i4) = qs;
  *(u16x4*)(kb + i4) = ks;
  if (idx < (B_ * S_) / 4) {
    f32x4 dv = *(const f32x4*)(delta + i4);
    f32x4 ds = {dv[0] * C, dv[1] * C, dv[2] * C, dv[3] * C};
    *(f32x4*)(dl + i4) = ds;
  }
}

// V [B,S,H,E] f32 -> V' [B,H,E,S] fp16 (tiled transpose)
__global__ __launch_bounds__(256) void prep_v(const float* __restrict__ v,
                                              u16* __restrict__ vb) {
  __shared__ float t[32][33];
  int bid = blockIdx.x;
  int et = bid & 1;
  int st = (bid >> 1) & 63;
  int h = (bid >> 7) & 7;
  int b = bid >> 10;
  int tx = threadIdx.x & 31;
  int ty = threadIdx.x >> 5;
#pragma unroll
  for (int k2 = 0; k2 < 4; ++k2) {
    int s = st * 32 + ty + 8 * k2;
    int e = et * 32 + tx;
    t[ty + 8 * k2][tx] = v[(((size_t)b * S_ + s) * H_ + h) * E_ + e];
  }
  __syncthreads();
#pragma unroll
  for (int k2 = 0; k2 < 4; ++k2) {
    int e = et * 32 + ty + 8 * k2;
    int s = st * 32 + tx;
    _Float16 hf = (_Float16)t[tx][ty + 8 * k2];
    vb[(((size_t)b * H_ + h) * E_ + e) * S_ + s] = __builtin_bit_cast(u16, hf);
  }
}

// One wave = 16 q-rows x 1024 s (half row-block). P kept entirely in VGPRs.
// Swapped QK^T: D = K*Q -> lane holds q = lane&15, s = 16t + 4*(lane>>4) + r.
__global__ __launch_bounds__(256, 2) void attn_fused(
    const u16* __restrict__ qb, const u16* __restrict__ kb,
    const u16* __restrict__ vbuf, const float* __restrict__ dl,
    float* __restrict__ out, float* __restrict__ oa) {
  __shared__ float psum[4][16];
  __shared__ float zr[4][16];
  __shared__ float ox[2][16][65];

  int bid = blockIdx.x;
  int swz = (bid & 7) * 256 + (bid >> 3);  // 2048 WGs, 8 XCDs
  int tid = threadIdx.x;
  int lane = tid & 63;
  int wave = tid >> 6;
  int pane = swz >> 6;        // 0..31  (b,h)
  int b = pane >> 3;
  int h = pane & 7;
  int qpair = swz & 63;       // 2 q-tiles per WG
  int qt = qpair * 2 + (wave >> 1);
  int m0 = qt * 16;
  int half = wave & 1;
  int s0 = half * 1024;
  int l15 = lane & 15, l4 = lane >> 4;

  // Q fragment (B operand): col q = l15, k(e) = 8*l4 + j
  const u16* qp = qb + (((size_t)b * L_ + (m0 + l15)) * H_ + h) * E_ + 8 * l4;
  bf16x8 qa0 = *(const bf16x8*)qp;
  bf16x8 qa1 = *(const bf16x8*)(qp + 32);

  const u16* kbase = kb + (((size_t)b * S_ + (s0 + l15)) * H_ + h) * E_ + 8 * l4;
  const float* dbase = dl + b * S_ + s0 + 4 * l4;

  // ---- QK^T sweep: P (f16 pairs) in registers + row sums ----
  f16x2 P[128];
  float sums = 0.f;
#pragma unroll
  for (int t = 0; t < 64; ++t) {
    const u16* kp = kbase + (size_t)t * (16 * H_ * E_);
    bf16x8 ka0 = *(const bf16x8*)kp;
    bf16x8 ka1 = *(const bf16x8*)(kp + 32);
    f32x4 dv = *(const f32x4*)(dbase + 16 * t);
    f32x4 acc = {0.f, 0.f, 0.f, 0.f};
    acc = __builtin_amdgcn_mfma_f32_16x16x32_bf16(ka0, qa0, acc, 0, 0, 0);
    acc = __builtin_amdgcn_mfma_f32_16x16x32_bf16(ka1, qa1, acc, 0, 0, 0);
    float p0 = __builtin_amdgcn_exp2f(acc[0] + dv[0]);
    float p1 = __builtin_amdgcn_exp2f(acc[1] + dv[1]);
    float p2 = __builtin_amdgcn_exp2f(acc[2] + dv[2]);
    float p3 = __builtin_amdgcn_exp2f(acc[3] + dv[3]);
    sums += (p0 + p1) + (p2 + p3);
    P[2 * t] = (f16x2){(_Float16)p0, (_Float16)p1};
    P[2 * t + 1] = (f16x2){(_Float16)p2, (_Float16)p3};
  }
  // reduce across the 4 l4 groups (all lanes end with sum for q = l15)
  sums += __shfl_xor(sums, 16, 64);
  sums += __shfl_xor(sums, 32, 64);
  if (lane < 16) psum[wave][lane] = sums;
  __syncthreads();
  float zinv = 1.f / (sums + psum[wave ^ 1][l15]);
  if (lane < 16) zr[wave][lane] = zinv;

  // ---- fused a-store + PV ----
  float* arow = oa + (((size_t)(b * H_ + h)) * L_ + (m0 + l15)) * S_ + s0 + 4 * l4;
  const u16* vb0 = vbuf + ((size_t)(b * H_ + h) * E_ + l15) * S_ + s0 + 8 * l4;
  f32x4 oacc[4];
#pragma unroll
  for (int et = 0; et < 4; ++et) oacc[et] = (f32x4){0.f, 0.f, 0.f, 0.f};

  int gsel = l4 >> 1;             // which tile of the pair
  int src0 = l15 + 16 * ((l4 & 1) * 2);
  int src1 = src0 + 16;

#pragma unroll
  for (int c = 0; c < 32; ++c) {
    // a-writes for tiles 2c, 2c+1 (each lane: 2 x f32x4, 64B segments)
#pragma unroll
    for (int tt = 0; tt < 2; ++tt) {
      int t = 2 * c + tt;
      f16x2 a0 = P[2 * t], a1 = P[2 * t + 1];
      f32x4 av = {(float)a0[0] * zinv, (float)a0[1] * zinv,
                  (float)a1[0] * zinv, (float)a1[1] * zinv};
      *(f32x4*)(arow + 16 * t) = av;
    }
    // build PV A-fragment (rows q=l15, k = s-local 8*l4+j) from registers
    u32 q0 = __builtin_bit_cast(u32, P[4 * c]);
    u32 q1 = __builtin_bit_cast(u32, P[4 * c + 1]);
    u32 q2 = __builtin_bit_cast(u32, P[4 * c + 2]);
    u32 q3 = __builtin_bit_cast(u32, P[4 * c + 3]);
    union { u32 w[4]; f16x8 v; } af;
    {
      u32 a = (u32)__shfl((int)q0, src0, 64);
      u32 bsh = (u32)__shfl((int)q2, src0, 64);
      af.w[0] = gsel ? bsh : a;
      a = (u32)__shfl((int)q1, src0, 64);
      bsh = (u32)__shfl((int)q3, src0, 64);
      af.w[1] = gsel ? bsh : a;
      a = (u32)__shfl((int)q0, src1, 64);
      bsh = (u32)__shfl((int)q2, src1, 64);
      af.w[2] = gsel ? bsh : a;
      a = (u32)__shfl((int)q1, src1, 64);
      bsh = (u32)__shfl((int)q3, src1, 64);
      af.w[3] = gsel ? bsh : a;
    }
#pragma unroll
    for (int et = 0; et < 4; ++et) {
      f16x8 vf = *(const f16x8*)(vb0 + (size_t)et * 16 * S_ + 32 * c);
      oacc[et] = __builtin_amdgcn_mfma_f32_16x16x32_f16(af.v, vf, oacc[et], 0, 0, 0);
    }
  }

  // ---- partner reduce (halves) + out store ----
  int pair = wave >> 1;
  if (half == 1) {
#pragma unroll
    for (int et = 0; et < 4; ++et)
#pragma unroll
      for (int r = 0; r < 4; ++r)
        ox[pair][4 * l4 + r][16 * et + l15] = oacc[et][r];
  }
  __syncthreads();
  if (half == 0) {
    float zq[4];
#pragma unroll
    for (int r = 0; r < 4; ++r) zq[r] = zr[wave][4 * l4 + r];
#pragma unroll
    for (int et = 0; et < 4; ++et)
#pragma unroll
      for (int r = 0; r < 4; ++r) {
        float o = oacc[et][r] + ox[pair][4 * l4 + r][16 * et + l15];
        out[(((size_t)b * L_ + (m0 + 4 * l4 + r)) * H_ + h) * E_ + 16 * et + l15] =
            o * zq[r];
      }
  }
}

extern "C" void kernel_launch(void* const* d_in, const int* in_sizes, int n_in,
                              void* d_out, int out_size, void* d_ws, size_t ws_size,
                              hipStream_t stream) {
  (void)in_sizes; (void)n_in; (void)out_size;
  const float* q = (const float*)d_in[0];
  const float* k = (const float*)d_in[1];
  const float* v = (const float*)d_in[2];
  const float* tau = (const float*)d_in[3];
  const float* delta = (const float*)d_in[4];
  float* out = (float*)d_out;
  float* oa = out + (size_t)B_ * L_ * H_ * E_;

  const size_t NQ = (size_t)B_ * L_ * H_ * E_;  // 4194304
  u16* qb = (u16*)d_ws;
  u16* kb = qb + NQ;
  u16* vb = kb + NQ;
  float* dl = (float*)(vb + NQ);
  size_t need = 3 * NQ * sizeof(u16) + (size_t)B_ * S_ * sizeof(float);
  if (ws_size < need) return;

  prep_qkd<<<4096, 256, 0, stream>>>(q, k, tau, delta, qb, kb, dl);
  prep_v<<<4096, 256, 0, stream>>>(v, vb);
  attn_fused<<<2048, 256, 0, stream>>>(qb, kb, vb, dl, out, oa);
}

// Round 4
// 360.761 us; speedup vs baseline: 1.4628x; 1.4628x over previous
//
#include <hip/hip_runtime.h>
#include <stdint.h>

#define B_ 4
#define L_ 2048
#define H_ 8
#define E_ 64
#define S_ 2048

typedef __bf16 bf16x8 __attribute__((ext_vector_type(8)));
typedef _Float16 f16x8 __attribute__((ext_vector_type(8)));
typedef _Float16 f16x4 __attribute__((ext_vector_type(4)));
typedef float f32x4 __attribute__((ext_vector_type(4)));
typedef unsigned short u16;
typedef u16 u16x4 __attribute__((ext_vector_type(4)));

__device__ __forceinline__ u16 f32_to_bf16(float f) {
  union { float f; uint32_t u; } x;
  x.f = f;
  uint32_t u = x.u;
  return (u16)((u + 0x7FFFu + ((u >> 16) & 1u)) >> 16);
}

// q' = bf16(q * tau[b]/sqrt(E) * log2e), k' = bf16(k), delta' = delta/sqrt(E)*log2e
__global__ __launch_bounds__(256) void prep_qkd(
    const float* __restrict__ q, const float* __restrict__ k,
    const float* __restrict__ tau, const float* __restrict__ delta,
    u16* __restrict__ qb, u16* __restrict__ kb, float* __restrict__ dl) {
  int idx = blockIdx.x * 256 + threadIdx.x;  // 0 .. 1048575
  int i4 = idx * 4;
  int b = i4 >> 20;
  const float C = 0.125f * 1.44269504088896f;
  float ts = tau[b] * C;
  f32x4 qv = *(const f32x4*)(q + i4);
  f32x4 kv = *(const f32x4*)(k + i4);
  u16x4 qs, ks;
#pragma unroll
  for (int j = 0; j < 4; ++j) {
    qs[j] = f32_to_bf16(qv[j] * ts);
    ks[j] = f32_to_bf16(kv[j]);
  }
  *(u16x4*)(qb + i4) = qs;
  *(u16x4*)(kb + i4) = ks;
  if (idx < (B_ * S_) / 4) {
    f32x4 dv = *(const f32x4*)(delta + i4);
    f32x4 ds = {dv[0] * C, dv[1] * C, dv[2] * C, dv[3] * C};
    *(f32x4*)(dl + i4) = ds;
  }
}

// V [B,S,H,E] f32 -> V' [B,H,E,S] fp16 (tiled transpose)
__global__ __launch_bounds__(256) void prep_v(const float* __restrict__ v,
                                              u16* __restrict__ vb) {
  __shared__ float t[32][33];
  int bid = blockIdx.x;
  int et = bid & 1;
  int st = (bid >> 1) & 63;
  int h = (bid >> 7) & 7;
  int b = bid >> 10;
  int tx = threadIdx.x & 31;
  int ty = threadIdx.x >> 5;
#pragma unroll
  for (int k2 = 0; k2 < 4; ++k2) {
    int s = st * 32 + ty + 8 * k2;
    int e = et * 32 + tx;
    t[ty + 8 * k2][tx] = v[(((size_t)b * S_ + s) * H_ + h) * E_ + e];
  }
  __syncthreads();
#pragma unroll
  for (int k2 = 0; k2 < 4; ++k2) {
    int e = et * 32 + ty + 8 * k2;
    int s = st * 32 + tx;
    _Float16 hf = (_Float16)t[tx][ty + 8 * k2];
    vb[(((size_t)b * H_ + h) * E_ + e) * S_ + s] = __builtin_bit_cast(u16, hf);
  }
}

// WG = 4 waves = one 16-row q-tile of one (b,h).
// P1: swapped QK^T (wave w covers s in [512w,512w+512)), exp -> f16 p into
//     XOR-swizzled LDS sc[q][s]; inline row-sum partials (2 shfls).
// P2: each wave sweeps ALL s-chunks: ds_read_b128 gives PV A-frag directly;
//     1 MFMA into own e-quarter; during own s-window also store normalized a.
__global__ __launch_bounds__(256, 2) void attn_fused(
    const u16* __restrict__ qb, const u16* __restrict__ kb,
    const u16* __restrict__ vbuf, const float* __restrict__ dl,
    float* __restrict__ out, float* __restrict__ oa) {
  __shared__ __align__(16) u16 sc[16 * 2048];  // 64 KB, swizzled f16 p
  __shared__ float psum[4][16];

  int bid = blockIdx.x;
  int swz = (bid & 7) * 512 + (bid >> 3);  // 4096 WGs, 8 XCDs
  int b = swz >> 10;
  int h = (swz >> 7) & 7;
  int qt = swz & 127;
  int m0 = qt * 16;
  int tid = threadIdx.x, lane = tid & 63, wave = tid >> 6;
  int l15 = lane & 15, l4 = lane >> 4;
  int s0 = wave * 512;
  int xm = (l15 & 7) << 4;  // XOR swizzle mask (bits 4-6)
  char* scb = (char*)sc;

  // Q fragment (B operand): col q = l15, k(e) = 8*l4 + j
  const u16* qp = qb + (((size_t)b * L_ + (m0 + l15)) * H_ + h) * E_ + 8 * l4;
  bf16x8 qa0 = *(const bf16x8*)qp;
  bf16x8 qa1 = *(const bf16x8*)(qp + 32);

  const u16* kbase = kb + (((size_t)b * S_ + (s0 + l15)) * H_ + h) * E_ + 8 * l4;
  const float* dbase = dl + b * S_ + s0 + 4 * l4;

  // ---- Phase 1 ----
  float sums = 0.f;
#pragma unroll 4
  for (int t = 0; t < 32; ++t) {
    const u16* kp = kbase + (size_t)t * (16 * H_ * E_);
    bf16x8 ka0 = *(const bf16x8*)kp;
    bf16x8 ka1 = *(const bf16x8*)(kp + 32);
    f32x4 dv = *(const f32x4*)(dbase + 16 * t);
    f32x4 acc = {0.f, 0.f, 0.f, 0.f};
    acc = __builtin_amdgcn_mfma_f32_16x16x32_bf16(ka0, qa0, acc, 0, 0, 0);
    acc = __builtin_amdgcn_mfma_f32_16x16x32_bf16(ka1, qa1, acc, 0, 0, 0);
    // lane holds D[s = 16t+4*l4+r][q = l15]
    float p0 = __builtin_amdgcn_exp2f(acc[0] + dv[0]);
    float p1 = __builtin_amdgcn_exp2f(acc[1] + dv[1]);
    float p2 = __builtin_amdgcn_exp2f(acc[2] + dv[2]);
    float p3 = __builtin_amdgcn_exp2f(acc[3] + dv[3]);
    sums += (p0 + p1) + (p2 + p3);
    f16x4 pv = {(_Float16)p0, (_Float16)p1, (_Float16)p2, (_Float16)p3};
    int off = (l15 << 12) + (((s0 << 1) + (t << 5) + (l4 << 3)) ^ xm);
    *(f16x4*)(scb + off) = pv;
  }
  // per-q row-sum over this wave's 512 s: combine the 4 l4 groups
  sums += __shfl_xor(sums, 16, 64);
  sums += __shfl_xor(sums, 32, 64);
  if (lane < 16) psum[wave][lane] = sums;
  __syncthreads();
  float zinv = 1.f / (psum[0][l15] + psum[1][l15] + psum[2][l15] + psum[3][l15]);

  // ---- Phase 2: fused a-store + PV ----
  float* arow = oa + (((size_t)(b * H_ + h)) * L_ + (m0 + l15)) * S_ + 8 * l4;
  const u16* vb0 =
      vbuf + ((size_t)(b * H_ + h) * E_ + 16 * wave + l15) * S_ + 8 * l4;
  f32x4 oaccA = {0.f, 0.f, 0.f, 0.f};
  f32x4 oaccB = {0.f, 0.f, 0.f, 0.f};

#pragma unroll 4
  for (int c = 0; c < 64; c += 2) {
#pragma unroll
    for (int cc = 0; cc < 2; ++cc) {
      int ci = c + cc;
      // A-frag: row q = l15, k(s) = 8*l4 + j  (swizzled b128 read)
      f16x8 af = *(const f16x8*)(scb + (l15 << 12) + (((ci << 6) + (l4 << 4)) ^ xm));
      f16x8 vf = *(const f16x8*)(vb0 + (ci << 5));
      if (cc == 0)
        oaccA = __builtin_amdgcn_mfma_f32_16x16x32_f16(af, vf, oaccA, 0, 0, 0);
      else
        oaccB = __builtin_amdgcn_mfma_f32_16x16x32_f16(af, vf, oaccB, 0, 0, 0);
      if ((ci >> 4) == wave) {  // own s-window: store normalized a
        f32x4 av0 = {(float)af[0] * zinv, (float)af[1] * zinv,
                     (float)af[2] * zinv, (float)af[3] * zinv};
        f32x4 av1 = {(float)af[4] * zinv, (float)af[5] * zinv,
                     (float)af[6] * zinv, (float)af[7] * zinv};
        *(f32x4*)(arow + (ci << 5)) = av0;
        *(f32x4*)(arow + (ci << 5) + 4) = av1;
      }
    }
  }

  // ---- out store: lane holds O[q=4*l4+r][e=16*wave+l15] ----
#pragma unroll
  for (int r = 0; r < 4; ++r) {
    int row = 4 * l4 + r;
    float zr = 1.f / (psum[0][row] + psum[1][row] + psum[2][row] + psum[3][row]);
    float o = oaccA[r] + oaccB[r];
    out[(((size_t)b * L_ + (m0 + row)) * H_ + h) * E_ + 16 * wave + l15] = o * zr;
  }
}

extern "C" void kernel_launch(void* const* d_in, const int* in_sizes, int n_in,
                              void* d_out, int out_size, void* d_ws, size_t ws_size,
                              hipStream_t stream) {
  (void)in_sizes; (void)n_in; (void)out_size;
  const float* q = (const float*)d_in[0];
  const float* k = (const float*)d_in[1];
  const float* v = (const float*)d_in[2];
  const float* tau = (const float*)d_in[3];
  const float* delta = (const float*)d_in[4];
  float* out = (float*)d_out;
  float* oa = out + (size_t)B_ * L_ * H_ * E_;

  const size_t NQ = (size_t)B_ * L_ * H_ * E_;  // 4194304
  u16* qb = (u16*)d_ws;
  u16* kb = qb + NQ;
  u16* vb = kb + NQ;
  float* dl = (float*)(vb + NQ);
  size_t need = 3 * NQ * sizeof(u16) + (size_t)B_ * S_ * sizeof(float);
  if (ws_size < need) return;

  prep_qkd<<<4096, 256, 0, stream>>>(q, k, tau, delta, qb, kb, dl);
  prep_v<<<4096, 256, 0, stream>>>(v, vb);
  attn_fused<<<4096, 256, 0, stream>>>(qb, kb, vb, dl, out, oa);
}

// Round 5
// 347.341 us; speedup vs baseline: 1.5193x; 1.0386x over previous
//
#include <hip/hip_runtime.h>
#include <stdint.h>

#define B_ 4
#define L_ 2048
#define H_ 8
#define E_ 64
#define S_ 2048

typedef __bf16 bf16x8 __attribute__((ext_vector_type(8)));
typedef _Float16 f16x8 __attribute__((ext_vector_type(8)));
typedef _Float16 f16x4 __attribute__((ext_vector_type(4)));
typedef float f32x4 __attribute__((ext_vector_type(4)));
typedef unsigned short u16;
typedef u16 u16x4 __attribute__((ext_vector_type(4)));

__device__ __forceinline__ u16 f32_to_bf16(float f) {
  union { float f; uint32_t u; } x;
  x.f = f;
  uint32_t u = x.u;
  return (u16)((u + 0x7FFFu + ((u >> 16) & 1u)) >> 16);
}

// q' = bf16(q * tau[b]/sqrt(E) * log2e), k' = bf16(k), delta' = delta/sqrt(E)*log2e
__global__ __launch_bounds__(256) void prep_qkd(
    const float* __restrict__ q, const float* __restrict__ k,
    const float* __restrict__ tau, const float* __restrict__ delta,
    u16* __restrict__ qb, u16* __restrict__ kb, float* __restrict__ dl) {
  int idx = blockIdx.x * 256 + threadIdx.x;  // 0 .. 1048575
  int i4 = idx * 4;
  int b = i4 >> 20;
  const float C = 0.125f * 1.44269504088896f;
  float ts = tau[b] * C;
  f32x4 qv = *(const f32x4*)(q + i4);
  f32x4 kv = *(const f32x4*)(k + i4);
  u16x4 qs, ks;
#pragma unroll
  for (int j = 0; j < 4; ++j) {
    qs[j] = f32_to_bf16(qv[j] * ts);
    ks[j] = f32_to_bf16(kv[j]);
  }
  *(u16x4*)(qb + i4) = qs;
  *(u16x4*)(kb + i4) = ks;
  if (idx < (B_ * S_) / 4) {
    f32x4 dv = *(const f32x4*)(delta + i4);
    f32x4 ds = {dv[0] * C, dv[1] * C, dv[2] * C, dv[3] * C};
    *(f32x4*)(dl + i4) = ds;
  }
}

// V [B,S,H,E] f32 -> V' [B,H,E,S] fp16 (tiled transpose)
__global__ __launch_bounds__(256) void prep_v(const float* __restrict__ v,
                                              u16* __restrict__ vb) {
  __shared__ float t[32][33];
  int bid = blockIdx.x;
  int et = bid & 1;
  int st = (bid >> 1) & 63;
  int h = (bid >> 7) & 7;
  int b = bid >> 10;
  int tx = threadIdx.x & 31;
  int ty = threadIdx.x >> 5;
#pragma unroll
  for (int k2 = 0; k2 < 4; ++k2) {
    int s = st * 32 + ty + 8 * k2;
    int e = et * 32 + tx;
    t[ty + 8 * k2][tx] = v[(((size_t)b * S_ + s) * H_ + h) * E_ + e];
  }
  __syncthreads();
#pragma unroll
  for (int k2 = 0; k2 < 4; ++k2) {
    int e = et * 32 + ty + 8 * k2;
    int s = st * 32 + tx;
    _Float16 hf = (_Float16)t[tx][ty + 8 * k2];
    vb[(((size_t)b * H_ + h) * E_ + e) * S_ + s] = __builtin_bit_cast(u16, hf);
  }
}

// WG = 4 waves = one 16-row q-tile of one (b,h).
// P1: swapped QK^T -> exp -> f16 p in XOR-swizzled LDS; inline row sums.
// P2: PV MFMA sweep (NO global stores).
// P3: pure streaming store of normalized a (LDS read -> cvt -> store only).
__global__ __launch_bounds__(256, 2) void attn_fused(
    const u16* __restrict__ qb, const u16* __restrict__ kb,
    const u16* __restrict__ vbuf, const float* __restrict__ dl,
    float* __restrict__ out, float* __restrict__ oa) {
  __shared__ __align__(16) u16 sc[16 * 2048];  // 64 KB swizzled f16 p
  __shared__ float psum[4][16];

  int bid = blockIdx.x;
  int swz = (bid & 7) * 512 + (bid >> 3);  // 4096 WGs, 8 XCDs
  int b = swz >> 10;
  int h = (swz >> 7) & 7;
  int qt = swz & 127;
  int m0 = qt * 16;
  int tid = threadIdx.x, lane = tid & 63, wave = tid >> 6;
  int l15 = lane & 15, l4 = lane >> 4;
  int s0 = wave * 512;
  int xm = (l15 & 7) << 4;  // XOR swizzle (bits 4-6), per-row
  char* scb = (char*)sc;

  // Q fragment (B operand): col q = l15, k(e) = 8*l4 + j
  const u16* qp = qb + (((size_t)b * L_ + (m0 + l15)) * H_ + h) * E_ + 8 * l4;
  bf16x8 qa0 = *(const bf16x8*)qp;
  bf16x8 qa1 = *(const bf16x8*)(qp + 32);

  const u16* kbase = kb + (((size_t)b * S_ + (s0 + l15)) * H_ + h) * E_ + 8 * l4;
  const float* dbase = dl + b * S_ + s0 + 4 * l4;

  // ---- Phase 1: QK^T + exp -> LDS, inline sums ----
  float sums = 0.f;
#pragma unroll 4
  for (int t = 0; t < 32; ++t) {
    const u16* kp = kbase + (size_t)t * (16 * H_ * E_);
    bf16x8 ka0 = *(const bf16x8*)kp;
    bf16x8 ka1 = *(const bf16x8*)(kp + 32);
    f32x4 dv = *(const f32x4*)(dbase + 16 * t);
    f32x4 acc = {0.f, 0.f, 0.f, 0.f};
    acc = __builtin_amdgcn_mfma_f32_16x16x32_bf16(ka0, qa0, acc, 0, 0, 0);
    acc = __builtin_amdgcn_mfma_f32_16x16x32_bf16(ka1, qa1, acc, 0, 0, 0);
    // lane holds D[s = s0+16t+4*l4+r][q = l15]
    float p0 = __builtin_amdgcn_exp2f(acc[0] + dv[0]);
    float p1 = __builtin_amdgcn_exp2f(acc[1] + dv[1]);
    float p2 = __builtin_amdgcn_exp2f(acc[2] + dv[2]);
    float p3 = __builtin_amdgcn_exp2f(acc[3] + dv[3]);
    sums += (p0 + p1) + (p2 + p3);
    f16x4 pv = {(_Float16)p0, (_Float16)p1, (_Float16)p2, (_Float16)p3};
    int off = (l15 << 12) + (((s0 << 1) + (t << 5) + (l4 << 3)) ^ xm);
    *(f16x4*)(scb + off) = pv;
  }
  sums += __shfl_xor(sums, 16, 64);
  sums += __shfl_xor(sums, 32, 64);
  if (lane < 16) psum[wave][lane] = sums;
  __syncthreads();

  // ---- Phase 2: PV only (no global stores) ----
  const u16* vb0 =
      vbuf + ((size_t)(b * H_ + h) * E_ + 16 * wave + l15) * S_ + 8 * l4;
  f32x4 oaccA = {0.f, 0.f, 0.f, 0.f};
  f32x4 oaccB = {0.f, 0.f, 0.f, 0.f};
#pragma unroll 4
  for (int c = 0; c < 64; c += 2) {
    f16x8 af0 = *(const f16x8*)(scb + (l15 << 12) + (((c << 6) + (l4 << 4)) ^ xm));
    f16x8 vf0 = *(const f16x8*)(vb0 + (c << 5));
    oaccA = __builtin_amdgcn_mfma_f32_16x16x32_f16(af0, vf0, oaccA, 0, 0, 0);
    f16x8 af1 = *(const f16x8*)(scb + (l15 << 12) + ((((c + 1) << 6) + (l4 << 4)) ^ xm));
    f16x8 vf1 = *(const f16x8*)(vb0 + ((c + 1) << 5));
    oaccB = __builtin_amdgcn_mfma_f32_16x16x32_f16(af1, vf1, oaccB, 0, 0, 0);
  }

  // out store: lane holds O[q = 4*l4+r][e = 16*wave + l15]
#pragma unroll
  for (int r = 0; r < 4; ++r) {
    int row = 4 * l4 + r;
    float zr = 1.f / (psum[0][row] + psum[1][row] + psum[2][row] + psum[3][row]);
    float o = oaccA[r] + oaccB[r];
    out[(((size_t)b * L_ + (m0 + row)) * H_ + h) * E_ + 16 * wave + l15] = o * zr;
  }

  // ---- Phase 3: pure streaming store of normalized a ----
  {
    int row = 4 * wave + l4;  // q-row this lane drains
    float zrow =
        1.f / (psum[0][row] + psum[1][row] + psum[2][row] + psum[3][row]);
    float* ar = oa + (((size_t)(b * H_ + h)) * L_ + (m0 + row)) * S_;
    int xr = (row & 7) << 4;
    const char* scr = scb + (row << 12);
#pragma unroll 4
    for (int it = 0; it < 16; ++it) {
      f16x8 pv = *(const f16x8*)(scr + (((it << 8) + (l15 << 4)) ^ xr));
      f32x4 lo = {(float)pv[0] * zrow, (float)pv[1] * zrow,
                  (float)pv[2] * zrow, (float)pv[3] * zrow};
      f32x4 hi = {(float)pv[4] * zrow, (float)pv[5] * zrow,
                  (float)pv[6] * zrow, (float)pv[7] * zrow};
      int col = it * 128 + l15 * 8;
      *(f32x4*)(ar + col) = lo;
      *(f32x4*)(ar + col + 4) = hi;
    }
  }
}

extern "C" void kernel_launch(void* const* d_in, const int* in_sizes, int n_in,
                              void* d_out, int out_size, void* d_ws, size_t ws_size,
                              hipStream_t stream) {
  (void)in_sizes; (void)n_in; (void)out_size;
  const float* q = (const float*)d_in[0];
  const float* k = (const float*)d_in[1];
  const float* v = (const float*)d_in[2];
  const float* tau = (const float*)d_in[3];
  const float* delta = (const float*)d_in[4];
  float* out = (float*)d_out;
  float* oa = out + (size_t)B_ * L_ * H_ * E_;

  const size_t NQ = (size_t)B_ * L_ * H_ * E_;  // 4194304
  u16* qb = (u16*)d_ws;
  u16* kb = qb + NQ;
  u16* vb = kb + NQ;
  float* dl = (float*)(vb + NQ);
  size_t need = 3 * NQ * sizeof(u16) + (size_t)B_ * S_ * sizeof(float);
  if (ws_size < need) return;

  prep_qkd<<<4096, 256, 0, stream>>>(q, k, tau, delta, qb, kb, dl);
  prep_v<<<4096, 256, 0, stream>>>(v, vb);
  attn_fused<<<4096, 256, 0, stream>>>(qb, kb, vb, dl, out, oa);
}

// Round 6
// 341.933 us; speedup vs baseline: 1.5434x; 1.0158x over previous
//
#include <hip/hip_runtime.h>
#include <stdint.h>

#define B_ 4
#define L_ 2048
#define H_ 8
#define E_ 64
#define S_ 2048

typedef __bf16 bf16x8 __attribute__((ext_vector_type(8)));
typedef _Float16 f16x8 __attribute__((ext_vector_type(8)));
typedef _Float16 f16x4 __attribute__((ext_vector_type(4)));
typedef float f32x4 __attribute__((ext_vector_type(4)));
typedef unsigned short u16;
typedef u16 u16x4 __attribute__((ext_vector_type(4)));

__device__ __forceinline__ u16 f32_to_bf16(float f) {
  union { float f; uint32_t u; } x;
  x.f = f;
  uint32_t u = x.u;
  return (u16)((u + 0x7FFFu + ((u >> 16) & 1u)) >> 16);
}

// q' = bf16(q * tau[b]/sqrt(E) * log2e), k' = bf16(k), delta' = delta/sqrt(E)*log2e
__global__ __launch_bounds__(256) void prep_qkd(
    const float* __restrict__ q, const float* __restrict__ k,
    const float* __restrict__ tau, const float* __restrict__ delta,
    u16* __restrict__ qb, u16* __restrict__ kb, float* __restrict__ dl) {
  int idx = blockIdx.x * 256 + threadIdx.x;  // 0 .. 1048575
  int i4 = idx * 4;
  int b = i4 >> 20;
  const float C = 0.125f * 1.44269504088896f;
  float ts = tau[b] * C;
  f32x4 qv = *(const f32x4*)(q + i4);
  f32x4 kv = *(const f32x4*)(k + i4);
  u16x4 qs, ks;
#pragma unroll
  for (int j = 0; j < 4; ++j) {
    qs[j] = f32_to_bf16(qv[j] * ts);
    ks[j] = f32_to_bf16(kv[j]);
  }
  *(u16x4*)(qb + i4) = qs;
  *(u16x4*)(kb + i4) = ks;
  if (idx < (B_ * S_) / 4) {
    f32x4 dv = *(const f32x4*)(delta + i4);
    f32x4 ds = {dv[0] * C, dv[1] * C, dv[2] * C, dv[3] * C};
    *(f32x4*)(dl + i4) = ds;
  }
}

// V [B,S,H,E] f32 -> V' [B,H,E,S] fp16 (tiled transpose)
__global__ __launch_bounds__(256) void prep_v(const float* __restrict__ v,
                                              u16* __restrict__ vb) {
  __shared__ float t[32][33];
  int bid = blockIdx.x;
  int et = bid & 1;
  int st = (bid >> 1) & 63;
  int h = (bid >> 7) & 7;
  int b = bid >> 10;
  int tx = threadIdx.x & 31;
  int ty = threadIdx.x >> 5;
#pragma unroll
  for (int k2 = 0; k2 < 4; ++k2) {
    int s = st * 32 + ty + 8 * k2;
    int e = et * 32 + tx;
    t[ty + 8 * k2][tx] = v[(((size_t)b * S_ + s) * H_ + h) * E_ + e];
  }
  __syncthreads();
#pragma unroll
  for (int k2 = 0; k2 < 4; ++k2) {
    int e = et * 32 + ty + 8 * k2;
    int s = st * 32 + tx;
    _Float16 hf = (_Float16)t[tx][ty + 8 * k2];
    vb[(((size_t)b * H_ + h) * E_ + e) * S_ + s] = __builtin_bit_cast(u16, hf);
  }
}

// WG = 8 waves (512 thr) = one 16-row q-tile of one (b,h). 2 WGs/CU -> 16 waves/CU.
// P1: swapped QK^T -> exp -> f16 p in XOR-swizzled LDS; wave covers 256 s.
// P2: PV MFMA; wave = (e-quarter, s-half); partner reduce via LDS.
// P3: pure streaming store of normalized a; wave drains 2 q-rows.
__global__ __launch_bounds__(512, 4) void attn_fused(
    const u16* __restrict__ qb, const u16* __restrict__ kb,
    const u16* __restrict__ vbuf, const float* __restrict__ dl,
    float* __restrict__ out, float* __restrict__ oa) {
  __shared__ __align__(16) u16 sc[16 * 2048];  // 64 KB swizzled f16 p
  __shared__ float psum[8][16];
  __shared__ float ox[4][16][17];

  int bid = blockIdx.x;
  int swz = (bid & 7) * 512 + (bid >> 3);  // 4096 WGs, 8 XCDs
  int b = swz >> 10;
  int h = (swz >> 7) & 7;
  int qt = swz & 127;
  int m0 = qt * 16;
  int tid = threadIdx.x, lane = tid & 63, wave = tid >> 6;  // wave 0..7
  int l15 = lane & 15, l4 = lane >> 4;
  int s0 = wave * 256;
  int xm = (l15 & 7) << 4;  // XOR swizzle (bits 4-6), per-row
  char* scb = (char*)sc;

  // Q fragment (B operand): col q = l15, k(e) = 8*l4 + j
  const u16* qp = qb + (((size_t)b * L_ + (m0 + l15)) * H_ + h) * E_ + 8 * l4;
  bf16x8 qa0 = *(const bf16x8*)qp;
  bf16x8 qa1 = *(const bf16x8*)(qp + 32);

  const u16* kbase = kb + (((size_t)b * S_ + (s0 + l15)) * H_ + h) * E_ + 8 * l4;
  const float* dbase = dl + b * S_ + s0 + 4 * l4;

  // ---- Phase 1: QK^T + exp -> LDS (16 tiles of 16 s), inline sums ----
  float sums = 0.f;
#pragma unroll 4
  for (int t = 0; t < 16; ++t) {
    const u16* kp = kbase + (size_t)t * (16 * H_ * E_);
    bf16x8 ka0 = *(const bf16x8*)kp;
    bf16x8 ka1 = *(const bf16x8*)(kp + 32);
    f32x4 dv = *(const f32x4*)(dbase + 16 * t);
    f32x4 acc = {0.f, 0.f, 0.f, 0.f};
    acc = __builtin_amdgcn_mfma_f32_16x16x32_bf16(ka0, qa0, acc, 0, 0, 0);
    acc = __builtin_amdgcn_mfma_f32_16x16x32_bf16(ka1, qa1, acc, 0, 0, 0);
    // lane holds D[s = s0+16t+4*l4+r][q = l15]
    float p0 = __builtin_amdgcn_exp2f(acc[0] + dv[0]);
    float p1 = __builtin_amdgcn_exp2f(acc[1] + dv[1]);
    float p2 = __builtin_amdgcn_exp2f(acc[2] + dv[2]);
    float p3 = __builtin_amdgcn_exp2f(acc[3] + dv[3]);
    sums += (p0 + p1) + (p2 + p3);
    f16x4 pv = {(_Float16)p0, (_Float16)p1, (_Float16)p2, (_Float16)p3};
    int off = (l15 << 12) + (((s0 << 1) + (t << 5) + (l4 << 3)) ^ xm);
    *(f16x4*)(scb + off) = pv;
  }
  sums += __shfl_xor(sums, 16, 64);
  sums += __shfl_xor(sums, 32, 64);
  if (lane < 16) psum[wave][lane] = sums;
  __syncthreads();

  float zq[2];  // zinv for the 2 rows this lane needs in P3 / reuse in P2
  // full-row zinv for any row r: sum psum[0..7][r]
  // P2 needs zinv[4*l4+r]; P3 needs zinv[2*wave + (lane>>5)]

  // ---- Phase 2: PV (no global stores). wave = (et = wave&3, s-half = wave>>2) ----
  {
    int et = wave & 3;
    int h2 = wave >> 2;
    const u16* vb0 =
        vbuf + ((size_t)(b * H_ + h) * E_ + 16 * et + l15) * S_ + h2 * 1024 + 8 * l4;
    const char* sch = scb + (l15 << 12) + (h2 << 11);
    f32x4 oaccA = {0.f, 0.f, 0.f, 0.f};
    f32x4 oaccB = {0.f, 0.f, 0.f, 0.f};
#pragma unroll 4
    for (int c = 0; c < 32; c += 2) {
      f16x8 af0 = *(const f16x8*)(sch + (((c << 6) + (l4 << 4)) ^ xm));
      f16x8 vf0 = *(const f16x8*)(vb0 + (c << 5));
      oaccA = __builtin_amdgcn_mfma_f32_16x16x32_f16(af0, vf0, oaccA, 0, 0, 0);
      f16x8 af1 = *(const f16x8*)(sch + ((((c + 1) << 6) + (l4 << 4)) ^ xm));
      f16x8 vf1 = *(const f16x8*)(vb0 + ((c + 1) << 5));
      oaccB = __builtin_amdgcn_mfma_f32_16x16x32_f16(af1, vf1, oaccB, 0, 0, 0);
    }
    oaccA += oaccB;
    if (h2 == 1) {
#pragma unroll
      for (int r = 0; r < 4; ++r) ox[et][4 * l4 + r][l15] = oaccA[r];
    }
    __syncthreads();
    if (h2 == 0) {
#pragma unroll
      for (int r = 0; r < 4; ++r) {
        int row = 4 * l4 + r;
        float zr = psum[0][row] + psum[1][row] + psum[2][row] + psum[3][row] +
                   psum[4][row] + psum[5][row] + psum[6][row] + psum[7][row];
        float o = oaccA[r] + ox[et][row][l15];
        out[(((size_t)b * L_ + (m0 + row)) * H_ + h) * E_ + 16 * et + l15] =
            o / zr;
      }
    }
  }

  // ---- Phase 3: pure streaming store of normalized a (2 rows per wave) ----
  {
    int row = 2 * wave + (lane >> 5);
    int l31 = lane & 31;
    float zrow = psum[0][row] + psum[1][row] + psum[2][row] + psum[3][row] +
                 psum[4][row] + psum[5][row] + psum[6][row] + psum[7][row];
    float zi = 1.f / zrow;
    float* ar = oa + (((size_t)(b * H_ + h)) * L_ + (m0 + row)) * S_;
    int xr = (row & 7) << 4;
    const char* scr = scb + (row << 12);
#pragma unroll 4
    for (int it = 0; it < 8; ++it) {
      f16x8 pv = *(const f16x8*)(scr + (((it << 9) + (l31 << 4)) ^ xr));
      f32x4 lo = {(float)pv[0] * zi, (float)pv[1] * zi,
                  (float)pv[2] * zi, (float)pv[3] * zi};
      f32x4 hi = {(float)pv[4] * zi, (float)pv[5] * zi,
                  (float)pv[6] * zi, (float)pv[7] * zi};
      int col = it * 256 + l31 * 8;
      *(f32x4*)(ar + col) = lo;
      *(f32x4*)(ar + col + 4) = hi;
    }
  }
}

extern "C" void kernel_launch(void* const* d_in, const int* in_sizes, int n_in,
                              void* d_out, int out_size, void* d_ws, size_t ws_size,
                              hipStream_t stream) {
  (void)in_sizes; (void)n_in; (void)out_size;
  const float* q = (const float*)d_in[0];
  const float* k = (const float*)d_in[1];
  const float* v = (const float*)d_in[2];
  const float* tau = (const float*)d_in[3];
  const float* delta = (const float*)d_in[4];
  float* out = (float*)d_out;
  float* oa = out + (size_t)B_ * L_ * H_ * E_;

  const size_t NQ = (size_t)B_ * L_ * H_ * E_;  // 4194304
  u16* qb = (u16*)d_ws;
  u16* kb = qb + NQ;
  u16* vb = kb + NQ;
  float* dl = (float*)(vb + NQ);
  size_t need = 3 * NQ * sizeof(u16) + (size_t)B_ * S_ * sizeof(float);
  if (ws_size < need) return;

  prep_qkd<<<4096, 256, 0, stream>>>(q, k, tau, delta, qb, kb, dl);
  prep_v<<<4096, 256, 0, stream>>>(v, vb);
  attn_fused<<<4096, 512, 0, stream>>>(qb, kb, vb, dl, out, oa);
}